// Round 6
// baseline (253.915 us; speedup 1.0000x reference)
//
#include <hip/hip_runtime.h>
#include <stdint.h>

#define TOK 8192      // B*S
#define DIM 1024
#define NE 8
#define NTILE 136     // max row-tiles: 128 + 8 ragged

typedef short bf16x8 __attribute__((ext_vector_type(8)));
typedef float f32x4 __attribute__((ext_vector_type(4)));

__device__ __forceinline__ unsigned short f2bf(float f) {
  unsigned int u = __float_as_uint(f);
  u += 0x7FFFu + ((u >> 16) & 1u);
  return (unsigned short)(u >> 16);
}

__device__ __forceinline__ void gl_lds16(const void* g, void* l) {
  __builtin_amdgcn_global_load_lds(
      (__attribute__((address_space(1))) unsigned int*)(g),
      (__attribute__((address_space(3))) unsigned int*)(l), 16, 0, 0);
}

// One wave per token: convert x row to bf16 + gating dots (fp64 acc) + write picks.
// NO global atomics (R1: 16384 same-line fetch-adds = 207 us serial).
// Block 0 also zeroes cnt (consumed by scatter_kernel, next in stream).
__global__ __launch_bounds__(256) void gate_kernel(
    const float* __restrict__ x, const float* __restrict__ gW,
    const float* __restrict__ gb, unsigned short* __restrict__ xb,
    int* __restrict__ eSel, float* __restrict__ wSel, int* __restrict__ cnt)
{
  if (blockIdx.x == 0 && threadIdx.x < NE) cnt[threadIdx.x] = 0;

  const int wave = threadIdx.x >> 6;
  const int lane = threadIdx.x & 63;
  const int t = blockIdx.x * 4 + wave;
  const float4* xrow = (const float4*)(x + (size_t)t * DIM);
  ushort4* xbrow = (ushort4*)(xb + (size_t)t * DIM);

  double acc[NE];
#pragma unroll
  for (int e = 0; e < NE; ++e) acc[e] = 0.0;

#pragma unroll
  for (int i = 0; i < 4; ++i) {
    const int j = i * 64 + lane;         // float4 index within row (0..255)
    float4 v = xrow[j];
    ushort4 pk;
    pk.x = f2bf(v.x); pk.y = f2bf(v.y); pk.z = f2bf(v.z); pk.w = f2bf(v.w);
    xbrow[j] = pk;
    const float* g = gW + (size_t)j * 4 * NE;
    float xv[4] = {v.x, v.y, v.z, v.w};
#pragma unroll
    for (int c = 0; c < 4; ++c) {
#pragma unroll
      for (int e = 0; e < NE; ++e)
        acc[e] += (double)xv[c] * (double)g[c * NE + e];
    }
  }
  // wave64 butterfly reduce (doubles)
#pragma unroll
  for (int off = 32; off > 0; off >>= 1) {
#pragma unroll
    for (int e = 0; e < NE; ++e)
      acc[e] += __shfl_xor(acc[e], off, 64);
  }

  if (lane == 0) {
    double s[NE];
#pragma unroll
    for (int e = 0; e < NE; ++e) {
      s[e] = acc[e] + (double)gb[e];
      if (s[e] < 1e-4) s[e] = 1e-4;     // clamp-min(EPS), TEMP=1
    }
    // top-2 by value on fp64 sums, ties -> lower index (strict > scan)
    int e0 = 0;
    for (int e = 1; e < NE; ++e) if (s[e] > s[e0]) e0 = e;
    int e1 = (e0 == 0) ? 1 : 0;
    for (int e = 0; e < NE; ++e) if (e != e0 && s[e] > s[e1]) e1 = e;
    // softmax + weights in fp32 (hardware exp)
    float m = (float)s[e0];             // e0 is the max
    float Z = 0.f, pf[NE];
#pragma unroll
    for (int e = 0; e < NE; ++e) { pf[e] = __expf((float)s[e] - m); Z += pf[e]; }
    float w0 = pf[e0] / Z; if (w0 < 0.1f) w0 = 0.1f;
    float w1 = pf[e1] / Z; if (w1 < 0.1f) w1 = 0.1f;
    const float inv = 0.5f / (w0 + w1);   // /total /K
    eSel[t * 2 + 0] = e0;
    eSel[t * 2 + 1] = e1;
    wSel[t * 2 + 0] = w0 * inv;
    wSel[t * 2 + 1] = w1 * inv;
  }
}

// Two-level scatter: LDS histogram per block (256 tokens), 8 global atomics per
// block for base offsets, then conflict-free placement. 256 global atomics total.
__global__ __launch_bounds__(256) void scatter_kernel(
    const int* __restrict__ eSel, const float* __restrict__ wSel,
    int* __restrict__ cnt, int* __restrict__ listTok, float* __restrict__ listW)
{
  __shared__ int lcnt[NE];
  __shared__ int base[NE];
  const int tid = threadIdx.x;
  if (tid < NE) lcnt[tid] = 0;
  __syncthreads();

  const int t = blockIdx.x * 256 + tid;
  const int e0 = eSel[t * 2 + 0];
  const int e1 = eSel[t * 2 + 1];
  const float w0 = wSel[t * 2 + 0];
  const float w1 = wSel[t * 2 + 1];
  const int l0 = atomicAdd(&lcnt[e0], 1);
  const int l1 = atomicAdd(&lcnt[e1], 1);
  __syncthreads();
  if (tid < NE) base[tid] = atomicAdd(&cnt[tid], lcnt[tid]);
  __syncthreads();

  const int p0 = base[e0] + l0;
  listTok[e0 * TOK + p0] = t * 2 + 0;   // token*2 + slot
  listW [e0 * TOK + p0] = w0;
  const int p1 = base[e1] + l1;
  listTok[e1 * TOK + p1] = t * 2 + 1;
  listW [e1 * TOK + p1] = w1;
}

// expert_W [e][d][f] fp32 -> brick-tiled bf16 Wt:
// Wt[e][fb][kc] is a 1 KB brick: 16 f-rows (f=fb*16+r) x 32 k (d=kc*32+k2),
// element offset r*32+k2. A wave's B-fragment load in moe_gemm is then
// 64 lanes x 16 B CONTIGUOUS (the ideal coalescing pattern).
__global__ __launch_bounds__(256) void transpose_w(
    const float* __restrict__ W, unsigned short* __restrict__ Wt)
{
  __shared__ float t[32 * 17 + 16];
  const int e  = blockIdx.x >> 6;
  const int fb = blockIdx.x & 63;
  const int f0 = fb * 16;
  const int tid = threadIdx.x;
  const float* Wb = W + (size_t)e * DIM * DIM + f0;
  unsigned short* Ob = Wt + ((size_t)(e * 64 + fb) * 32) * 512;

  for (int kc = 0; kc < 32; ++kc) {
    const int d0 = kc * 32;
    __syncthreads();                       // protect t from prev read-phase
#pragma unroll
    for (int h = 0; h < 512; h += 256) {
      const int idx = tid + h;             // k2 = idx>>4, r = idx&15
      t[(idx >> 4) * 17 + (idx & 15)] = Wb[(size_t)(d0 + (idx >> 4)) * DIM + (idx & 15)];
    }
    __syncthreads();
#pragma unroll
    for (int h = 0; h < 512; h += 256) {
      const int o = tid + h;               // r = o>>5, k2 = o&31
      Ob[(size_t)kc * 512 + o] = f2bf(t[(o & 31) * 17 + (o >> 5)]);
    }
  }
}

// Grouped GEMM: 128(tokens) x 128(f) tile, BK=32, 16x16x32 bf16 MFMA.
// R6: (a) mapping reverted to cT=bx&7 -> XCD = cT -> per-XCD B working set =
// 8 experts x one 128-col panel = 2 MB, L2-RESIDENT (R2's accidental win; the
// R4/R5 dId%8 swizzle blew it up to ~16 MB -> B missed L2 every k-iter).
// (b) B register double-buffer ACROSS the barrier: b(k+1) issued right after
// barrier k, consumed at iter k+1 -> MFMAs never wait on in-flight B, and the
// barrier's forced vmcnt(0) drains loads issued a full iteration earlier.
// A stays in LDS (dbuf, 1 barrier, XOR swizzle) — A is shared by 2 waves.
__global__ __launch_bounds__(256) void moe_gemm(
    const unsigned short* __restrict__ xb, const unsigned short* __restrict__ Wt,
    const float* __restrict__ eb, const int* __restrict__ cnt,
    const int* __restrict__ listTok, const float* __restrict__ listW,
    float* __restrict__ yslot)
{
  const int dId = blockIdx.x >> 3;
  const int cT  = blockIdx.x & 7;       // XCD = bx%8 = cT  (B L2 residency)
  int e = -1, r0 = 0, rows = 0, accT = 0;
#pragma unroll
  for (int ee = 0; ee < NE; ++ee) {
    const int c = cnt[ee];
    const int nt = (c + 127) >> 7;
    if (dId >= accT && dId < accT + nt) {
      e = ee; r0 = (dId - accT) * 128;
      rows = c - r0; if (rows > 128) rows = 128;
    }
    accT += nt;
  }
  if (e < 0) return;

  __shared__ __align__(16) unsigned short As[2][128 * 32];  // 64B/row, swizzled
  __shared__ int   tid_s[128];
  __shared__ float w_s[128];

  const int tid = threadIdx.x;
  if (tid < 128) {
    if (tid < rows) {
      tid_s[tid] = listTok[e * TOK + r0 + tid];
      w_s[tid]   = listW [e * TOK + r0 + tid];
    } else {
      tid_s[tid] = 0;     // safe dummy row (token 0) — never stored
      w_s[tid]   = 0.0f;
    }
  }
  __syncthreads();

  const int w    = tid >> 6;
  const int lane = tid & 63;
  // A staging: lane fills LDS quarter-slot (lane&3) of row w*32+(lane>>2)
  // [+16]; slot q holds GLOBAL quarter q ^ ((row>>1)&3) = q ^ ((lane>>3)&3).
  const int qsrc = (lane & 3) ^ ((lane >> 3) & 3);
  const int rA0  = w * 32 + (lane >> 2);
  const int rA1  = rA0 + 16;
  const unsigned short* srcA0 = xb + (size_t)(tid_s[rA0] >> 1) * DIM + qsrc * 8;
  const unsigned short* srcA1 = xb + (size_t)(tid_s[rA1] >> 1) * DIM + qsrc * 8;

  const int wr = w >> 1, wc = w & 1;
  const int mrow = lane & 15;
  const int qg   = lane >> 4;                      // k-quarter consumed
  const int qsA  = (qg ^ ((mrow >> 1) & 3)) * 8;   // swizzled LDS offset (elems)

  // B brick pointers (one per nt), advanced +512 elems (1 KB) per k-chunk.
  const unsigned short* pB[4];
#pragma unroll
  for (int nt = 0; nt < 4; ++nt)
    pB[nt] = Wt + ((size_t)(e * 64 + cT * 8 + wc * 4 + nt) * 32) * 512
                + mrow * 32 + qg * 8;

  f32x4 acc[4][4];
#pragma unroll
  for (int i = 0; i < 4; ++i)
#pragma unroll
    for (int j = 0; j < 4; ++j)
      acc[i][j] = {0.f, 0.f, 0.f, 0.f};

  bf16x8 b0[4], b1[4];
  // prologue: load b(0), stage A(0) into As[0]
#pragma unroll
  for (int nt = 0; nt < 4; ++nt) { b0[nt] = *(const bf16x8*)pB[nt]; pB[nt] += 512; }
  gl_lds16(srcA0, &As[0][w * 1024]);
  gl_lds16(srcA1, &As[0][w * 1024 + 512]);

  for (int kc = 0; kc < DIM / 32; kc += 2) {
    // ---- even sub-iter: consume b0 + As[0]; prefetch b1(kc+1), DMA A(kc+1)
    __syncthreads();                     // As[0] DMA complete; prev reads done
#pragma unroll
    for (int nt = 0; nt < 4; ++nt) { b1[nt] = *(const bf16x8*)pB[nt]; pB[nt] += 512; }
    {
      const int k1 = (kc + 1) * 32;      // kc+1 <= 31 always
      gl_lds16(srcA0 + k1, &As[1][w * 1024]);
      gl_lds16(srcA1 + k1, &As[1][w * 1024 + 512]);
    }
    {
      bf16x8 af[4];
#pragma unroll
      for (int mt = 0; mt < 4; ++mt)
        af[mt] = *(const bf16x8*)&As[0][(wr * 64 + mt * 16 + mrow) * 32 + qsA];
#pragma unroll
      for (int nt = 0; nt < 4; ++nt)
#pragma unroll
        for (int mt = 0; mt < 4; ++mt)
          acc[mt][nt] = __builtin_amdgcn_mfma_f32_16x16x32_bf16(
              af[mt], b0[nt], acc[mt][nt], 0, 0, 0);
    }
    // ---- odd sub-iter: consume b1 + As[1]; prefetch b0(kc+2), DMA A(kc+2)
    __syncthreads();
    if (kc + 2 < DIM / 32) {
#pragma unroll
      for (int nt = 0; nt < 4; ++nt) { b0[nt] = *(const bf16x8*)pB[nt]; pB[nt] += 512; }
      const int k2 = (kc + 2) * 32;
      gl_lds16(srcA0 + k2, &As[0][w * 1024]);
      gl_lds16(srcA1 + k2, &As[0][w * 1024 + 512]);
    }
    {
      bf16x8 af[4];
#pragma unroll
      for (int mt = 0; mt < 4; ++mt)
        af[mt] = *(const bf16x8*)&As[1][(wr * 64 + mt * 16 + mrow) * 32 + qsA];
#pragma unroll
      for (int nt = 0; nt < 4; ++nt)
#pragma unroll
        for (int mt = 0; mt < 4; ++mt)
          acc[mt][nt] = __builtin_amdgcn_mfma_f32_16x16x32_bf16(
              af[mt], b1[nt], acc[mt][nt], 0, 0, 0);
    }
  }

  // epilogue: C/D map col=lane&15, row=(lane>>4)*4+r
  const int colBase = cT * 128 + wc * 64 + mrow;
  float bias[4];
#pragma unroll
  for (int nt = 0; nt < 4; ++nt)
    bias[nt] = eb[(size_t)e * DIM + colBase + nt * 16];
#pragma unroll
  for (int mt = 0; mt < 4; ++mt) {
#pragma unroll
    for (int r = 0; r < 4; ++r) {
      const int rloc = wr * 64 + mt * 16 + (lane >> 4) * 4 + r;
      if (rloc < rows) {
        const int tk    = tid_s[rloc];
        const float wgt = w_s[rloc];
        float* dst = yslot + ((size_t)(tk & 1) * TOK + (size_t)(tk >> 1)) * DIM;
#pragma unroll
        for (int nt = 0; nt < 4; ++nt)
          dst[colBase + nt * 16] = wgt * (acc[mt][nt][r] + bias[nt]);
      }
    }
  }
}

__global__ __launch_bounds__(256) void combine(
    const float4* __restrict__ y0, const float4* __restrict__ y1,
    float4* __restrict__ out)
{
  const size_t i = (size_t)blockIdx.x * 256 + threadIdx.x;
  float4 a = y0[i], b = y1[i];
  float4 o;
  o.x = a.x + b.x; o.y = a.y + b.y; o.z = a.z + b.z; o.w = a.w + b.w;
  out[i] = o;
}

extern "C" void kernel_launch(void* const* d_in, const int* in_sizes, int n_in,
                              void* d_out, int out_size, void* d_ws, size_t ws_size,
                              hipStream_t stream)
{
  const float* x  = (const float*)d_in[0];
  const float* gW = (const float*)d_in[1];
  const float* gb = (const float*)d_in[2];
  const float* eW = (const float*)d_in[3];
  const float* eb = (const float*)d_in[4];
  float* out = (float*)d_out;

  char* p = (char*)d_ws;
  unsigned short* xb = (unsigned short*)p;  p += (size_t)TOK * DIM * 2;       // 16 MB
  unsigned short* Wt = (unsigned short*)p;  p += (size_t)NE * DIM * DIM * 2;  // 16 MB
  float* yslot = (float*)p;                 p += (size_t)2 * TOK * DIM * 4;   // 64 MB
  int* cnt = (int*)p;                       p += 256;
  int* listTok = (int*)p;                   p += (size_t)NE * TOK * 4;
  float* listW = (float*)p;                 p += (size_t)NE * TOK * 4;

  // eSel/wSel alias the head of yslot: consumed by scatter_kernel BEFORE
  // moe_gemm overwrites yslot (stream-ordered). Saves 128 KB of ws.
  int*   eSel = (int*)yslot;                  // TOK*2 ints = 64 KB
  float* wSel = (float*)(yslot + TOK * 2);    // TOK*2 floats = 64 KB

  gate_kernel<<<TOK / 4, 256, 0, stream>>>(x, gW, gb, xb, eSel, wSel, cnt);
  scatter_kernel<<<TOK / 256, 256, 0, stream>>>(eSel, wSel, cnt, listTok, listW);
  transpose_w<<<NE * 64, 256, 0, stream>>>(eW, Wt);
  moe_gemm<<<NTILE * 8, 256, 0, stream>>>(xb, Wt, eb, cnt, listTok, listW, yslot);
  combine<<<TOK * DIM / 4 / 256, 256, 0, stream>>>(
      (const float4*)yslot, (const float4*)yslot + (size_t)TOK * DIM / 4, (float4*)out);
}

// Round 7
// 214.030 us; speedup vs baseline: 1.1864x; 1.1864x over previous
//
#include <hip/hip_runtime.h>
#include <hip/hip_fp16.h>
#include <stdint.h>

#define TOK 8192      // B*S
#define DIM 1024
#define NE 8
#define NTILE 136     // max row-tiles: 128 + 8 ragged

typedef short bf16x8 __attribute__((ext_vector_type(8)));
typedef float f32x4 __attribute__((ext_vector_type(4)));

__device__ __forceinline__ unsigned short f2bf(float f) {
  unsigned int u = __float_as_uint(f);
  u += 0x7FFFu + ((u >> 16) & 1u);
  return (unsigned short)(u >> 16);
}

__device__ __forceinline__ void gl_lds16(const void* g, void* l) {
  __builtin_amdgcn_global_load_lds(
      (__attribute__((address_space(1))) unsigned int*)(g),
      (__attribute__((address_space(3))) unsigned int*)(l), 16, 0, 0);
}

// One wave per token: convert x row to bf16 + gating dots (fp64 acc) + write picks.
// NO global atomics (R1: 16384 same-line fetch-adds = 207 us serial).
// R7: gW staged to LDS transposed [e][d] -> per i-iter 8 conflict-free
// ds_read_b128 instead of 128 scattered global dword loads per wave.
__global__ __launch_bounds__(256) void gate_kernel(
    const float* __restrict__ x, const float* __restrict__ gW,
    const float* __restrict__ gb, unsigned short* __restrict__ xb,
    int* __restrict__ eSel, float* __restrict__ wSel, int* __restrict__ cnt)
{
  if (blockIdx.x == 0 && threadIdx.x < NE) cnt[threadIdx.x] = 0;

  __shared__ float gWs[NE * DIM];   // 32 KB, [e][d]
#pragma unroll
  for (int h = 0; h < 8; ++h) {
    const int m = threadIdx.x + h * 256;       // float4 id over gW (2048)
    float4 v = ((const float4*)gW)[m];
    const int d = m >> 1, e0 = (m & 1) * 4;    // gW is [d][e]: elem 4m+c = (d, e0+c)
    gWs[(e0 + 0) * DIM + d] = v.x;
    gWs[(e0 + 1) * DIM + d] = v.y;
    gWs[(e0 + 2) * DIM + d] = v.z;
    gWs[(e0 + 3) * DIM + d] = v.w;
  }
  __syncthreads();

  const int wave = threadIdx.x >> 6;
  const int lane = threadIdx.x & 63;
  const int t = blockIdx.x * 4 + wave;
  const float4* xrow = (const float4*)(x + (size_t)t * DIM);
  ushort4* xbrow = (ushort4*)(xb + (size_t)t * DIM);

  double acc[NE];
#pragma unroll
  for (int e = 0; e < NE; ++e) acc[e] = 0.0;

#pragma unroll
  for (int i = 0; i < 4; ++i) {
    const int j = i * 64 + lane;         // float4 index within row (0..255)
    float4 v = xrow[j];
    ushort4 pk;
    pk.x = f2bf(v.x); pk.y = f2bf(v.y); pk.z = f2bf(v.z); pk.w = f2bf(v.w);
    xbrow[j] = pk;
#pragma unroll
    for (int e = 0; e < NE; ++e) {
      float4 gv = *(const float4*)&gWs[e * DIM + j * 4];
      acc[e] += (double)v.x * (double)gv.x + (double)v.y * (double)gv.y
              + (double)v.z * (double)gv.z + (double)v.w * (double)gv.w;
    }
  }
  // wave64 butterfly reduce (doubles)
#pragma unroll
  for (int off = 32; off > 0; off >>= 1) {
#pragma unroll
    for (int e = 0; e < NE; ++e)
      acc[e] += __shfl_xor(acc[e], off, 64);
  }

  if (lane == 0) {
    double s[NE];
#pragma unroll
    for (int e = 0; e < NE; ++e) {
      s[e] = acc[e] + (double)gb[e];
      if (s[e] < 1e-4) s[e] = 1e-4;     // clamp-min(EPS), TEMP=1
    }
    // top-2 by value on fp64 sums, ties -> lower index (strict > scan)
    int e0 = 0;
    for (int e = 1; e < NE; ++e) if (s[e] > s[e0]) e0 = e;
    int e1 = (e0 == 0) ? 1 : 0;
    for (int e = 0; e < NE; ++e) if (e != e0 && s[e] > s[e1]) e1 = e;
    // softmax + weights in fp32 (hardware exp)
    float m = (float)s[e0];             // e0 is the max
    float Z = 0.f, pf[NE];
#pragma unroll
    for (int e = 0; e < NE; ++e) { pf[e] = __expf((float)s[e] - m); Z += pf[e]; }
    float w0 = pf[e0] / Z; if (w0 < 0.1f) w0 = 0.1f;
    float w1 = pf[e1] / Z; if (w1 < 0.1f) w1 = 0.1f;
    const float inv = 0.5f / (w0 + w1);   // /total /K
    eSel[t * 2 + 0] = e0;
    eSel[t * 2 + 1] = e1;
    wSel[t * 2 + 0] = w0 * inv;
    wSel[t * 2 + 1] = w1 * inv;
  }
}

// Two-level scatter: LDS histogram per block (256 tokens), 8 global atomics per
// block for base offsets, then conflict-free placement. 256 global atomics total.
__global__ __launch_bounds__(256) void scatter_kernel(
    const int* __restrict__ eSel, const float* __restrict__ wSel,
    int* __restrict__ cnt, int* __restrict__ listTok, float* __restrict__ listW)
{
  __shared__ int lcnt[NE];
  __shared__ int base[NE];
  const int tid = threadIdx.x;
  if (tid < NE) lcnt[tid] = 0;
  __syncthreads();

  const int t = blockIdx.x * 256 + tid;
  const int e0 = eSel[t * 2 + 0];
  const int e1 = eSel[t * 2 + 1];
  const float w0 = wSel[t * 2 + 0];
  const float w1 = wSel[t * 2 + 1];
  const int l0 = atomicAdd(&lcnt[e0], 1);
  const int l1 = atomicAdd(&lcnt[e1], 1);
  __syncthreads();
  if (tid < NE) base[tid] = atomicAdd(&cnt[tid], lcnt[tid]);
  __syncthreads();

  const int p0 = base[e0] + l0;
  listTok[e0 * TOK + p0] = t * 2 + 0;   // token*2 + slot
  listW [e0 * TOK + p0] = w0;
  const int p1 = base[e1] + l1;
  listTok[e1 * TOK + p1] = t * 2 + 1;
  listW [e1 * TOK + p1] = w1;
}

// expert_W [e][d][f] fp32 -> Wt [e][f][d] bf16 (flat, same layout R4's gemm
// staging uses). R7: 32-wide f-blocks x 64-deep k-tiles so BOTH the read of W
// (per k-row) and the write of Wt (per f-row) touch 128 B contiguous — the old
// version read 64 B per 4 KB line (~2x W overfetch).
__global__ __launch_bounds__(256) void transpose_w(
    const float* __restrict__ W, unsigned short* __restrict__ Wt)
{
  __shared__ float t2[64 * 33];          // [k2][f], padded
  const int e  = blockIdx.x >> 5;
  const int fb = blockIdx.x & 31;        // 32-col f-block
  const int f0 = fb * 32;
  const int tid = threadIdx.x;
  const float* Wb = W + (size_t)e * DIM * DIM + f0;
  unsigned short* Ob = Wt + ((size_t)e * DIM + f0) * DIM;

  for (int kc = 0; kc < 16; ++kc) {      // 64 k-rows per pass
    const int d0 = kc * 64;
    __syncthreads();                     // protect t2 from prev read-phase
#pragma unroll
    for (int h = 0; h < 8; ++h) {
      const int idx = tid + h * 256;     // k2 = idx>>5 (0..63), f = idx&31
      t2[(idx >> 5) * 33 + (idx & 31)] = Wb[(size_t)(d0 + (idx >> 5)) * DIM + (idx & 31)];
    }
    __syncthreads();
#pragma unroll
    for (int h = 0; h < 8; ++h) {
      const int o = tid + h * 256;       // f = o>>6 (0..31), k2 = o&63
      Ob[(size_t)(o >> 6) * DIM + d0 + (o & 63)] = f2bf(t2[(o & 63) * 33 + (o >> 6)]);
    }
  }
}

// Grouped GEMM: 128(tokens) x 128(f) tile, BK=32, 16x16x32 bf16 MFMA.
// R7 = R4's best-measured structure verbatim (A+B LDS, dbuf, 1 barrier/iter,
// XOR swizzle, dId-major mapping: XCD = bx%8 = dId%8 -> the 8 cT siblings of a
// row-tile share an XCD -> A-gather L2 locality; FETCH 95 MB vs 115 cT-major).
// Only change: yslot is fp16 (halves GEMM write + combine read traffic).
__global__ __launch_bounds__(256) void moe_gemm(
    const unsigned short* __restrict__ xb, const unsigned short* __restrict__ Wt,
    const float* __restrict__ eb, const int* __restrict__ cnt,
    const int* __restrict__ listTok, const float* __restrict__ listW,
    __half* __restrict__ yslot)
{
  const int dId = blockIdx.x % NTILE;
  const int cT  = blockIdx.x / NTILE;
  int e = -1, r0 = 0, rows = 0, accT = 0;
#pragma unroll
  for (int ee = 0; ee < NE; ++ee) {
    const int c = cnt[ee];
    const int nt = (c + 127) >> 7;
    if (dId >= accT && dId < accT + nt) {
      e = ee; r0 = (dId - accT) * 128;
      rows = c - r0; if (rows > 128) rows = 128;
    }
    accT += nt;
  }
  if (e < 0) return;

  __shared__ __align__(16) unsigned short As[2][128 * 32];  // 64B/row, swizzled
  __shared__ __align__(16) unsigned short Bs[2][128 * 32];
  __shared__ int   tid_s[128];
  __shared__ float w_s[128];

  const int tid = threadIdx.x;
  if (tid < 128) {
    if (tid < rows) {
      tid_s[tid] = listTok[e * TOK + r0 + tid];
      w_s[tid]   = listW [e * TOK + r0 + tid];
    } else {
      tid_s[tid] = 0;     // safe dummy row (token 0) — never stored
      w_s[tid]   = 0.0f;
    }
  }
  __syncthreads();

  const int w    = tid >> 6;
  const int lane = tid & 63;
  // Staging: lane i fills LDS quarter-slot (i&3) of tile-row w*32+(i>>2) [+16].
  // Swizzle: slot q holds GLOBAL quarter q ^ ((row>>1)&3) = q ^ ((lane>>3)&3).
  const int qsrc = (lane & 3) ^ ((lane >> 3) & 3);
  const int rA0  = w * 32 + (lane >> 2);
  const int rA1  = rA0 + 16;
  const unsigned short* srcA0 = xb + (size_t)(tid_s[rA0] >> 1) * DIM + qsrc * 8;
  const unsigned short* srcA1 = xb + (size_t)(tid_s[rA1] >> 1) * DIM + qsrc * 8;
  const unsigned short* srcB0 = Wt + ((size_t)e * DIM + cT * 128 + rA0) * DIM + qsrc * 8;
  const unsigned short* srcB1 = Wt + ((size_t)e * DIM + cT * 128 + rA1) * DIM + qsrc * 8;

  const int wr = w >> 1, wc = w & 1;
  const int mrow = lane & 15;
  const int qg   = lane >> 4;                      // global k-quarter consumed
  const int qsA  = (qg ^ ((mrow >> 1) & 3)) * 8;   // swizzled LDS offset (elems)

  f32x4 acc[4][4];
#pragma unroll
  for (int i = 0; i < 4; ++i)
#pragma unroll
    for (int j = 0; j < 4; ++j)
      acc[i][j] = {0.f, 0.f, 0.f, 0.f};

  // prologue: stage k-chunk 0 into buffer 0
  gl_lds16(srcA0, &As[0][w * 1024]);
  gl_lds16(srcA1, &As[0][w * 1024 + 512]);
  gl_lds16(srcB0, &Bs[0][w * 1024]);
  gl_lds16(srcB1, &Bs[0][w * 1024 + 512]);

#pragma unroll 2
  for (int kc = 0; kc < DIM / 32; ++kc) {
    const int cur = kc & 1;
    __syncthreads();              // buf[cur] DMA complete; prev reads drained
    if (kc < DIM / 32 - 1) {      // stage k+1 into the other buffer NOW
      const int k1 = (kc + 1) * 32;
      unsigned short* a = &As[cur ^ 1][w * 1024];
      unsigned short* b = &Bs[cur ^ 1][w * 1024];
      gl_lds16(srcA0 + k1, a);
      gl_lds16(srcA1 + k1, a + 512);
      gl_lds16(srcB0 + k1, b);
      gl_lds16(srcB1 + k1, b + 512);
    }
    bf16x8 af[4], bfr[4];
#pragma unroll
    for (int mt = 0; mt < 4; ++mt)
      af[mt] = *(const bf16x8*)&As[cur][(wr * 64 + mt * 16 + mrow) * 32 + qsA];
#pragma unroll
    for (int nt = 0; nt < 4; ++nt)
      bfr[nt] = *(const bf16x8*)&Bs[cur][(wc * 64 + nt * 16 + mrow) * 32 + qsA];
#pragma unroll
    for (int mt = 0; mt < 4; ++mt)
#pragma unroll
      for (int nt = 0; nt < 4; ++nt)
        acc[mt][nt] = __builtin_amdgcn_mfma_f32_16x16x32_bf16(
            af[mt], bfr[nt], acc[mt][nt], 0, 0, 0);
  }

  // epilogue: C/D map col=lane&15, row=(lane>>4)*4+r
  const int colBase = cT * 128 + wc * 64 + mrow;
  float bias[4];
#pragma unroll
  for (int nt = 0; nt < 4; ++nt)
    bias[nt] = eb[(size_t)e * DIM + colBase + nt * 16];
#pragma unroll
  for (int mt = 0; mt < 4; ++mt) {
#pragma unroll
    for (int r = 0; r < 4; ++r) {
      const int rloc = wr * 64 + mt * 16 + (lane >> 4) * 4 + r;
      if (rloc < rows) {
        const int tk    = tid_s[rloc];
        const float wgt = w_s[rloc];
        __half* dst = yslot + ((size_t)(tk & 1) * TOK + (size_t)(tk >> 1)) * DIM;
#pragma unroll
        for (int nt = 0; nt < 4; ++nt)
          dst[colBase + nt * 16] = __float2half(wgt * (acc[mt][nt][r] + bias[nt]));
      }
    }
  }
}

__global__ __launch_bounds__(256) void combine(
    const __half* __restrict__ y0, const __half* __restrict__ y1,
    float4* __restrict__ out)
{
  const size_t i = (size_t)blockIdx.x * 256 + threadIdx.x;  // float4 index
  const ushort4 ua = ((const ushort4*)y0)[i];
  const ushort4 ub = ((const ushort4*)y1)[i];
  const __half* ah = (const __half*)&ua;
  const __half* bh = (const __half*)&ub;
  float4 o;
  o.x = __half2float(ah[0]) + __half2float(bh[0]);
  o.y = __half2float(ah[1]) + __half2float(bh[1]);
  o.z = __half2float(ah[2]) + __half2float(bh[2]);
  o.w = __half2float(ah[3]) + __half2float(bh[3]);
  out[i] = o;
}

extern "C" void kernel_launch(void* const* d_in, const int* in_sizes, int n_in,
                              void* d_out, int out_size, void* d_ws, size_t ws_size,
                              hipStream_t stream)
{
  const float* x  = (const float*)d_in[0];
  const float* gW = (const float*)d_in[1];
  const float* gb = (const float*)d_in[2];
  const float* eW = (const float*)d_in[3];
  const float* eb = (const float*)d_in[4];
  float* out = (float*)d_out;

  char* p = (char*)d_ws;
  unsigned short* xb = (unsigned short*)p;  p += (size_t)TOK * DIM * 2;       // 16 MB
  unsigned short* Wt = (unsigned short*)p;  p += (size_t)NE * DIM * DIM * 2;  // 16 MB
  __half* yslot = (__half*)p;               p += (size_t)2 * TOK * DIM * 2;   // 32 MB
  int* cnt = (int*)p;                       p += 256;
  int* listTok = (int*)p;                   p += (size_t)NE * TOK * 4;
  float* listW = (float*)p;                 p += (size_t)NE * TOK * 4;

  // eSel/wSel alias the head of yslot: consumed by scatter_kernel BEFORE
  // moe_gemm overwrites yslot (stream-ordered). Saves 128 KB of ws.
  int*   eSel = (int*)yslot;                        // TOK*2 ints = 64 KB
  float* wSel = (float*)((char*)yslot + TOK * 8);   // TOK*2 floats = 64 KB

  gate_kernel<<<TOK / 4, 256, 0, stream>>>(x, gW, gb, xb, eSel, wSel, cnt);
  scatter_kernel<<<TOK / 256, 256, 0, stream>>>(eSel, wSel, cnt, listTok, listW);
  transpose_w<<<NE * 32, 256, 0, stream>>>(eW, Wt);
  moe_gemm<<<NTILE * 8, 256, 0, stream>>>(xb, Wt, eb, cnt, listTok, listW, yslot);
  combine<<<TOK * DIM / 4 / 256, 256, 0, stream>>>(
      yslot, yslot + (size_t)TOK * DIM, (float4*)out);
}